// Round 15
// baseline (335.425 us; speedup 1.0000x reference)
//
#include <hip/hip_runtime.h>
#include <hip/hip_bf16.h>
#include <stdint.h>

typedef __attribute__((ext_vector_type(8))) short bf16x8;
typedef __attribute__((ext_vector_type(4))) float f32x4;
typedef __attribute__((ext_vector_type(4))) unsigned int u32x4;

#define MFMA __builtin_amdgcn_mfma_f32_16x16x32_bf16

__device__ __forceinline__ ushort f2bf(float v) {
    __hip_bfloat16 b = __float2bfloat16(v);
    return *reinterpret_cast<ushort*>(&b);
}

// Unit mapping: group g (=degree), main m-th unit: h = g + 63*m (m=0..15);
// extra unit of group g<16: h = 1008+g.
// Register chunk layout: chunk j (0..31) = main units of groups 2j (k 0..15), 2j+1 (k 16..31);
// chunk 32 = extras (k = g for g<16, rest zero).
__global__ void prep_all(const float* __restrict__ W1, const float* __restrict__ W2,
                         const float* __restrict__ W3, const float* __restrict__ b1,
                         const float* __restrict__ b2,
                         ushort* __restrict__ W2f2, ushort* __restrict__ W2g2,
                         ushort* __restrict__ W1f, ushort* __restrict__ W3f,
                         float* __restrict__ b1s2, float* __restrict__ b1e,
                         float* __restrict__ b2s2, float* __restrict__ b2e)
{
    int idx = blockIdx.x * 256 + threadIdx.x;
    if (idx < 63 * 33 * 512) {
        int d = idx / (33 * 512); int rem = idx - d * 33 * 512;
        int kc = rem >> 9, r = rem & 511;
        int lane = r >> 3, e = r & 7;
        int col = lane & 15, s = ((lane >> 4) << 3) + e;
        int hout = d + 63 * col;
        float v = 0.f;
        if (kc < 32) {
            int g = 2 * kc + (s >> 4), m = s & 15;
            if (g <= 62) v = W2[(size_t)(g + 63 * m) * 1024 + hout];
        } else if (s < 16) {
            v = W2[(size_t)(1008 + s) * 1024 + hout];
        }
        W2f2[idx] = f2bf(v);
    }
    if (idx < 16 * 9 * 512) {
        int d = idx / (9 * 512); int rem = idx - d * 9 * 512;
        int j = rem >> 9, r = rem & 511;
        int lane = r >> 3, e = r & 7;
        int col = lane & 15, s = ((lane >> 4) << 3) + e;
        float v = 0.f;
        if (col == 0) {
            int hout = 1008 + d;
            if (j < 8) {
                int g = 2 * j + (s >> 4), m = s & 15;
                if (g <= 62) v = W2[(size_t)(g + 63 * m) * 1024 + hout];
            } else if (s < 16) {
                v = W2[(size_t)(1008 + s) * 1024 + hout];
            }
        }
        W2g2[idx] = f2bf(v);
    }
    if (idx < 63 * 2048) {
        int d = idx >> 11; int rem = idx & 2047;
        int kc2 = rem >> 10, nt = (rem >> 9) & 1, r = rem & 511;
        int lane = r >> 3, e = r & 7;
        int col = lane & 15, k = kc2 * 32 + ((lane >> 4) << 3) + e;
        float v = 0.f;
        if (nt == 0) v = W1[(size_t)k * 1024 + d + 63 * col];
        else if (d < 16 && col == 0) v = W1[(size_t)k * 1024 + 1008 + d];
        W1f[idx] = f2bf(v);
    }
    if (idx < 63 * 8 * 512) {
        int d = idx >> 12; int rem = idx & 4095;
        int cb = rem >> 9, r = rem & 511;
        int lane = r >> 3, e = r & 7;
        int ncol = lane & 15, s = ((lane >> 4) << 3) + e;
        int c = cb * 16 + ncol;
        float v = 0.f;
        if (s < 16) v = W3[(size_t)(d + 63 * s) * 128 + c];
        else if (s == 16 && d < 16) v = W3[(size_t)(1008 + d) * 128 + c];
        W3f[idx] = f2bf(v);
    }
    if (idx < 1008) {
        int d = idx >> 4, m = idx & 15;
        b1s2[idx] = b1[d + 63 * m];
        b2s2[idx] = b2[d + 63 * m];
    }
    if (idx < 16) { b1e[idx] = b1[1008 + idx]; b2e[idx] = b2[1008 + idx]; }
}

// phase b: h2 group = sum over chunks of h1f[kc] x W2 B-frag; chunk list = 0..CM-1, then 32.
// bb: 6-deep rolling prefetch, 2 accumulator chains; gg (T2): 2-deep prefetch.
template<int CM, bool T2>
__device__ __forceinline__ void phase_b(const char* __restrict__ w2p,
                                        const char* __restrict__ w2gp,
                                        const bf16x8 (&h1f)[33], int lane16,
                                        f32x4& o1, f32x4& o2)
{
    constexpr int N = CM + 1;
    constexpr int PF = (N < 6) ? N : 6;
    bf16x8 bb[6];
    bf16x8 gg[2];
    #pragma unroll
    for (int i = 0; i < PF; ++i) {
        int kc = (i < CM) ? i : 32;
        bb[i] = *(const bf16x8*)(w2p + kc * 1024 + lane16);
    }
    if constexpr (T2) {
        #pragma unroll
        for (int i = 0; i < 2; ++i)
            gg[i] = *(const bf16x8*)(w2gp + i * 1024 + lane16);
    }
    f32x4 c0 = {0,0,0,0}, c1 = {0,0,0,0};
    f32x4 g0 = {0,0,0,0}, g1 = {0,0,0,0};
    #pragma unroll
    for (int i = 0; i < N; ++i) {
        int kc = (i < CM) ? i : 32;
        bf16x8 a = h1f[kc];
        bf16x8 b = bb[i % 6];
        if (i & 1) c1 = MFMA(a, b, c1, 0, 0, 0);
        else       c0 = MFMA(a, b, c0, 0, 0, 0);
        if constexpr (T2) {
            bf16x8 g = gg[i & 1];
            if (i & 1) g1 = MFMA(a, g, g1, 0, 0, 0);
            else       g0 = MFMA(a, g, g0, 0, 0, 0);
            if (i + 2 < N)
                gg[i & 1] = *(const bf16x8*)(w2gp + (i + 2) * 1024 + lane16);
        }
        if (i + 6 < N) {
            int kn = (i + 6 < CM) ? (i + 6) : 32;
            bb[i % 6] = *(const bf16x8*)(w2p + kn * 1024 + lane16);
        }
    }
    o1 = c0 + c1;
    if constexpr (T2) o2 = g0 + g1;
}

// 4 waves/WG, each wave owns a private 16-row batch slice: NO __syncthreads anywhere.
__global__ __launch_bounds__(256, 2)
void maf_main(const float* __restrict__ U, const float* __restrict__ b3,
              const ushort* __restrict__ W2f2, const ushort* __restrict__ W2g2,
              const ushort* __restrict__ W1f, const ushort* __restrict__ W3f,
              const float* __restrict__ b1s2, const float* __restrict__ b1e,
              const float* __restrict__ b2s2, const float* __restrict__ b2e,
              float* __restrict__ out)
{
    __shared__ char smem[4*1024 + 4*1024 + 4*1024 + 4*2304 + 4*64];  // 21.8 KB/WG
    const int tid = threadIdx.x;
    const int w = tid >> 6, lane = tid & 63;
    const int r16 = lane & 15, q = lane >> 4;
    const int lane16 = lane << 4;
    char*   stgm = smem + w * 1024;                      // chunk-pair transpose staging
    char*   stge = smem + 4096 + w * 1024;               // extras staging (accumulating)
    char*   h2s  = smem + 8192 + w * 1024;               // h2 group staging
    ushort* xbs  = (ushort*)(smem + 12288 + w * 2304);   // [16][72] bf16 x mirror
    float*  lgd  = (float*)(smem + 21504 + w * 64);      // [16] logdet
    const int grow0 = blockIdx.x * 64 + w * 16;

    {
        u32x4 z = {0u, 0u, 0u, 0u};
        for (int i = lane; i < 64; i += 64) *(u32x4*)(stge + i * 16) = z;
        for (int i = lane; i < 64; i += 64) *(u32x4*)(h2s + i * 16) = z;
        for (int i = lane; i < 576; i += 64) ((uint32_t*)xbs)[i] = 0u;
        if (lane < 16) lgd[lane] = 0.f;
    }

    bf16x8 h1f[33];
    #pragma unroll
    for (int i = 0; i < 33; ++i) h1f[i] = (bf16x8){0,0,0,0,0,0,0,0};

    // output acc: am = mu cols (0..63), al = ls cols (64..127); tile n = cols n*16..
    f32x4 am0={0,0,0,0},am1={0,0,0,0},am2={0,0,0,0},am3={0,0,0,0};
    f32x4 al0={0,0,0,0},al1={0,0,0,0},al2={0,0,0,0},al3={0,0,0,0};

    for (int t = 0; t < 64; ++t) {
        const int tt = t >> 4, oc = t & 15;
        const float b3mu = b3[t], b3ls = b3[64 + t];
        float uu[4] = {0.f, 0.f, 0.f, 0.f};
        if (r16 == oc) {
            #pragma unroll
            for (int e = 0; e < 4; ++e)
                uu[e] = U[(size_t)(grow0 + q * 4 + e) * 64 + t];
        }

        if (t > 0) {
            const int d = t - 1;
            const int jc = d >> 1;

            // ---- phase a (MFMA): finalize h1 group d ----
            {
                const char* w1p = (const char*)W1f + (size_t)d * 4096 + lane16;
                bf16x8 wf00 = *(const bf16x8*)(w1p);
                bf16x8 wf10 = *(const bf16x8*)(w1p + 2048);
                bf16x8 xa0 = *(const bf16x8*)(xbs + r16 * 72 + q * 8);
                bf16x8 xa1 = *(const bf16x8*)(xbs + r16 * 72 + 32 + q * 8);
                f32x4 h = {0,0,0,0};
                h = MFMA(xa0, wf00, h, 0, 0, 0);
                h = MFMA(xa1, wf10, h, 0, 0, 0);
                float bb1 = b1s2[d * 16 + r16];
                #pragma unroll
                for (int e = 0; e < 4; ++e) {
                    int row = q * 4 + e;
                    ushort hv = f2bf(fmaxf(h[e] + bb1, 0.f));
                    *(ushort*)(stgm + ((row * 64 + ((d & 1) << 5) + r16 * 2) ^ ((row & 3) << 4))) = hv;
                    if (!(d & 1))
                        *(ushort*)(stgm + ((row * 64 + 32 + r16 * 2) ^ ((row & 3) << 4))) = 0;
                }
                if (d < 16) {                              // extra (17th) unit
                    bf16x8 wf01 = *(const bf16x8*)(w1p + 1024);
                    bf16x8 wf11 = *(const bf16x8*)(w1p + 3072);
                    f32x4 g = {0,0,0,0};
                    g = MFMA(xa0, wf01, g, 0, 0, 0);
                    g = MFMA(xa1, wf11, g, 0, 0, 0);
                    if (r16 == 0) {
                        float be = b1e[d];
                        #pragma unroll
                        for (int e = 0; e < 4; ++e) {
                            int row = q * 4 + e;
                            ushort hv = f2bf(fmaxf(g[e] + be, 0.f));
                            *(ushort*)(stge + ((row * 64 + d * 2) ^ ((row & 3) << 4))) = hv;
                        }
                    }
                }
            }
            // read back updated chunk frag(s) into registers
            {
                bf16x8 nf = *(const bf16x8*)(stgm + ((r16 * 64 + q * 16) ^ ((r16 & 3) << 4)));
                switch (jc) {
                    case 0:  h1f[0]=nf;  break; case 1:  h1f[1]=nf;  break;
                    case 2:  h1f[2]=nf;  break; case 3:  h1f[3]=nf;  break;
                    case 4:  h1f[4]=nf;  break; case 5:  h1f[5]=nf;  break;
                    case 6:  h1f[6]=nf;  break; case 7:  h1f[7]=nf;  break;
                    case 8:  h1f[8]=nf;  break; case 9:  h1f[9]=nf;  break;
                    case 10: h1f[10]=nf; break; case 11: h1f[11]=nf; break;
                    case 12: h1f[12]=nf; break; case 13: h1f[13]=nf; break;
                    case 14: h1f[14]=nf; break; case 15: h1f[15]=nf; break;
                    case 16: h1f[16]=nf; break; case 17: h1f[17]=nf; break;
                    case 18: h1f[18]=nf; break; case 19: h1f[19]=nf; break;
                    case 20: h1f[20]=nf; break; case 21: h1f[21]=nf; break;
                    case 22: h1f[22]=nf; break; case 23: h1f[23]=nf; break;
                    case 24: h1f[24]=nf; break; case 25: h1f[25]=nf; break;
                    case 26: h1f[26]=nf; break; case 27: h1f[27]=nf; break;
                    case 28: h1f[28]=nf; break; case 29: h1f[29]=nf; break;
                    case 30: h1f[30]=nf; break; default: h1f[31]=nf; break;
                }
                if (d < 16)
                    h1f[32] = *(const bf16x8*)(stge + ((r16 * 64 + q * 16) ^ ((r16 & 3) << 4)));
            }

            // ---- phase b (MFMA, register A-frags, streamed B-frags) ----
            f32x4 o1, o2 = {0,0,0,0};
            const char* w2p = (const char*)W2f2 + (size_t)d * 33 * 1024;
            const char* w2gp = (const char*)W2g2 + (size_t)d * 9 * 1024;
            if (t <= 16)      phase_b<8,  true >(w2p, w2gp, h1f, lane16, o1, o2);
            else if (t <= 28) phase_b<14, false>(w2p, w2gp, h1f, lane16, o1, o2);
            else if (t <= 40) phase_b<20, false>(w2p, w2gp, h1f, lane16, o1, o2);
            else if (t <= 52) phase_b<26, false>(w2p, w2gp, h1f, lane16, o1, o2);
            else              phase_b<32, false>(w2p, w2gp, h1f, lane16, o1, o2);

            // ---- phase c: preload mu-tiles (f0..f3), h2 staging, ls frags inline ----
            {
                const char* w3p = (const char*)W3f + (size_t)d * 8192 + lane16;
                bf16x8 f0 = *(const bf16x8*)(w3p);
                bf16x8 f1 = *(const bf16x8*)(w3p + 1024);
                bf16x8 f2 = *(const bf16x8*)(w3p + 2048);
                bf16x8 f3 = *(const bf16x8*)(w3p + 3072);
                float bb2 = b2s2[d * 16 + r16];
                #pragma unroll
                for (int e = 0; e < 4; ++e) {
                    int row = q * 4 + e;
                    ushort hv = f2bf(fmaxf(o1[e] + bb2, 0.f));
                    *(ushort*)(h2s + ((row * 64 + r16 * 2) ^ ((row & 3) << 4))) = hv;
                }
                if (r16 == 0) {
                    float be2 = (d < 16) ? b2e[d] : 0.f;
                    #pragma unroll
                    for (int e = 0; e < 4; ++e) {
                        int row = q * 4 + e;
                        ushort hv = (d < 16) ? f2bf(fmaxf(o2[e] + be2, 0.f)) : (ushort)0;
                        *(ushort*)(h2s + ((row * 64 + 32) ^ ((row & 3) << 4))) = hv;
                    }
                }
                bf16x8 ha = *(const bf16x8*)(h2s + ((r16 * 64 + q * 16) ^ ((r16 & 3) << 4)));
                am0 = MFMA(ha, f0, am0, 0, 0, 0);
                am1 = MFMA(ha, f1, am1, 0, 0, 0);
                am2 = MFMA(ha, f2, am2, 0, 0, 0);
                am3 = MFMA(ha, f3, am3, 0, 0, 0);
                al0 = MFMA(ha, *(const bf16x8*)(w3p + 4096), al0, 0, 0, 0);
                al1 = MFMA(ha, *(const bf16x8*)(w3p + 5120), al1, 0, 0, 0);
                al2 = MFMA(ha, *(const bf16x8*)(w3p + 6144), al2, 0, 0, 0);
                al3 = MFMA(ha, *(const bf16x8*)(w3p + 7168), al3, 0, 0, 0);
            }
        }

        // ---- phase d: col t is final; owner lanes form x_t ----
        {
            f32x4 vm = (tt == 0) ? am0 : (tt == 1) ? am1 : (tt == 2) ? am2 : am3;
            f32x4 vl = (tt == 0) ? al0 : (tt == 1) ? al1 : (tt == 2) ? al2 : al3;
            if (r16 == oc) {
                #pragma unroll
                for (int e = 0; e < 4; ++e) {
                    int row = q * 4 + e;
                    float mu = vm[e] + b3mu;
                    float ls = vl[e] + b3ls;
                    float xv = uu[e] * expf(ls) + mu;
                    out[(size_t)(grow0 + row) * 64 + t] = xv;
                    xbs[row * 72 + t] = f2bf(xv);
                    lgd[row] += ls;
                }
            }
        }
    }

    if (lane < 16) out[(size_t)32768 * 64 + grow0 + lane] = lgd[lane];
}

extern "C" void kernel_launch(void* const* d_in, const int* in_sizes, int n_in,
                              void* d_out, int out_size, void* d_ws, size_t ws_size,
                              hipStream_t stream) {
    const float* U  = (const float*)d_in[0];
    const float* W1 = (const float*)d_in[1];
    const float* b1 = (const float*)d_in[2];
    const float* W2 = (const float*)d_in[3];
    const float* b2 = (const float*)d_in[4];
    const float* W3 = (const float*)d_in[5];
    const float* b3 = (const float*)d_in[6];
    float* out = (float*)d_out;

    char* ws = (char*)d_ws;
    ushort* W2f2 = (ushort*)ws;                      // 2,128,896 B
    ushort* W2g2 = (ushort*)(ws + 2128896);          //   147,456 B
    ushort* W1f  = (ushort*)(ws + 2276352);          //   258,048 B
    ushort* W3f  = (ushort*)(ws + 2534400);          //   516,096 B
    float*  b1s2 = (float*)(ws + 3050496);           //     4,096 B (1008 used)
    float*  b1e  = (float*)(ws + 3054592);           //       128 B
    float*  b2s2 = (float*)(ws + 3054720);           //     4,032 B
    float*  b2e  = (float*)(ws + 3058752);           //        64 B

    prep_all<<<4160, 256, 0, stream>>>(W1, W2, W3, b1, b2,
                                       W2f2, W2g2, W1f, W3f, b1s2, b1e, b2s2, b2e);
    maf_main<<<512, 256, 0, stream>>>(U, b3, W2f2, W2g2, W1f, W3f,
                                      b1s2, b1e, b2s2, b2e, out);
}

// Round 16
// 292.642 us; speedup vs baseline: 1.1462x; 1.1462x over previous
//
#include <hip/hip_runtime.h>
#include <hip/hip_bf16.h>
#include <stdint.h>

typedef __attribute__((ext_vector_type(8))) short bf16x8;
typedef __attribute__((ext_vector_type(4))) float f32x4;
typedef __attribute__((ext_vector_type(4))) unsigned int u32x4;

#define MFMA __builtin_amdgcn_mfma_f32_16x16x32_bf16

__device__ __forceinline__ ushort f2bf(float v) {
    __hip_bfloat16 b = __float2bfloat16(v);
    return *reinterpret_cast<ushort*>(&b);
}

// Unit mapping: group g (=degree), main m-th unit: h = g + 63*m (m=0..15);
// extra unit of group g<16: h = 1008+g.
// Register chunk layout: chunk j (0..31) = main units of groups 2j (k 0..15), 2j+1 (k 16..31);
// chunk 32 = extras (k = g for g<16, rest zero).
//
// W2f2 [63 d][33 kc][512] bf16 B-frags: col=lane&15 -> out unit d+63*col; k-slot s=(lane>>4)*8+e
//      -> in unit per chunk mapping (zero-padded).
// W2g2 [16 d][9 j][512]  B-frags for out unit 1008+d (col 0 only); j<8 -> chunk j, j=8 -> extras.
// W1f  [63 d][2 kc2][2 nt][512] phase-a B-frags (k=input dim, col=unit, zero-pad past gsz).
// W3f  [63 d][8 cb][512] phase-c B-frags (k-slot s -> h2 unit d+63*s; s=16 -> 1008+d when d<16).
__global__ void prep_all(const float* __restrict__ W1, const float* __restrict__ W2,
                         const float* __restrict__ W3, const float* __restrict__ b1,
                         const float* __restrict__ b2,
                         ushort* __restrict__ W2f2, ushort* __restrict__ W2g2,
                         ushort* __restrict__ W1f, ushort* __restrict__ W3f,
                         float* __restrict__ b1s2, float* __restrict__ b1e,
                         float* __restrict__ b2s2, float* __restrict__ b2e)
{
    int idx = blockIdx.x * 256 + threadIdx.x;
    if (idx < 63 * 33 * 512) {
        int d = idx / (33 * 512); int rem = idx - d * 33 * 512;
        int kc = rem >> 9, r = rem & 511;
        int lane = r >> 3, e = r & 7;
        int col = lane & 15, s = ((lane >> 4) << 3) + e;
        int hout = d + 63 * col;
        float v = 0.f;
        if (kc < 32) {
            int g = 2 * kc + (s >> 4), m = s & 15;
            if (g <= 62) v = W2[(size_t)(g + 63 * m) * 1024 + hout];
        } else if (s < 16) {
            v = W2[(size_t)(1008 + s) * 1024 + hout];
        }
        W2f2[idx] = f2bf(v);
    }
    if (idx < 16 * 9 * 512) {
        int d = idx / (9 * 512); int rem = idx - d * 9 * 512;
        int j = rem >> 9, r = rem & 511;
        int lane = r >> 3, e = r & 7;
        int col = lane & 15, s = ((lane >> 4) << 3) + e;
        float v = 0.f;
        if (col == 0) {
            int hout = 1008 + d;
            if (j < 8) {
                int g = 2 * j + (s >> 4), m = s & 15;
                if (g <= 62) v = W2[(size_t)(g + 63 * m) * 1024 + hout];
            } else if (s < 16) {
                v = W2[(size_t)(1008 + s) * 1024 + hout];
            }
        }
        W2g2[idx] = f2bf(v);
    }
    if (idx < 63 * 2048) {
        int d = idx >> 11; int rem = idx & 2047;
        int kc2 = rem >> 10, nt = (rem >> 9) & 1, r = rem & 511;
        int lane = r >> 3, e = r & 7;
        int col = lane & 15, k = kc2 * 32 + ((lane >> 4) << 3) + e;
        float v = 0.f;
        if (nt == 0) v = W1[(size_t)k * 1024 + d + 63 * col];
        else if (d < 16 && col == 0) v = W1[(size_t)k * 1024 + 1008 + d];
        W1f[idx] = f2bf(v);
    }
    if (idx < 63 * 8 * 512) {
        int d = idx >> 12; int rem = idx & 4095;
        int cb = rem >> 9, r = rem & 511;
        int lane = r >> 3, e = r & 7;
        int n = lane & 15, s = ((lane >> 4) << 3) + e;
        int c = cb * 16 + n;
        float v = 0.f;
        if (s < 16) v = W3[(size_t)(d + 63 * s) * 128 + c];
        else if (s == 16 && d < 16) v = W3[(size_t)(1008 + d) * 128 + c];
        W3f[idx] = f2bf(v);
    }
    if (idx < 1008) {
        int d = idx >> 4, m = idx & 15;
        b1s2[idx] = b1[d + 63 * m];
        b2s2[idx] = b2[d + 63 * m];
    }
    if (idx < 16) { b1e[idx] = b1[1008 + idx]; b2e[idx] = b2[1008 + idx]; }
}

// phase b: h2 group = sum over chunks of h1f[kc] x W2 B-frag; chunk list = 0..CM-1, then 32.
template<int CM, bool T2>
__device__ __forceinline__ void phase_b(const char* __restrict__ w2p,
                                        const char* __restrict__ w2gp,
                                        const bf16x8 (&h1f)[33], int lane16,
                                        f32x4& o1, f32x4& o2)
{
    constexpr int N = CM + 1;
    constexpr int PF = (N < 4) ? N : 4;
    bf16x8 bb[4]; bf16x8 gg[4];
    #pragma unroll
    for (int i = 0; i < PF; ++i) {
        int kc = (i < CM) ? i : 32;
        bb[i] = *(const bf16x8*)(w2p + kc * 1024 + lane16);
        if constexpr (T2) gg[i] = *(const bf16x8*)(w2gp + i * 1024 + lane16);
    }
    f32x4 c0 = {0,0,0,0}, c1 = {0,0,0,0}, c2 = {0,0,0,0}, c3 = {0,0,0,0};
    f32x4 g0 = {0,0,0,0}, g1 = {0,0,0,0};
    __builtin_amdgcn_s_setprio(1);
    #pragma unroll
    for (int i = 0; i < N; ++i) {
        int kc = (i < CM) ? i : 32;
        bf16x8 a = h1f[kc];
        bf16x8 b = bb[i & 3];
        if ((i & 3) == 0)      c0 = MFMA(a, b, c0, 0, 0, 0);
        else if ((i & 3) == 1) c1 = MFMA(a, b, c1, 0, 0, 0);
        else if ((i & 3) == 2) c2 = MFMA(a, b, c2, 0, 0, 0);
        else                   c3 = MFMA(a, b, c3, 0, 0, 0);
        if constexpr (T2) {
            bf16x8 g = gg[i & 3];
            if (i & 1) g1 = MFMA(a, g, g1, 0, 0, 0);
            else       g0 = MFMA(a, g, g0, 0, 0, 0);
        }
        if (i + 4 < N) {
            int kn = (i + 4 < CM) ? (i + 4) : 32;
            bb[i & 3] = *(const bf16x8*)(w2p + kn * 1024 + lane16);
            if constexpr (T2) gg[i & 3] = *(const bf16x8*)(w2gp + (i + 4) * 1024 + lane16);
        }
    }
    __builtin_amdgcn_s_setprio(0);
    o1 = (c0 + c1) + (c2 + c3);
    if constexpr (T2) o2 = g0 + g1;
}

// 4 waves/WG, each wave owns a private 16-row batch slice; h1 history in registers.
__global__ __launch_bounds__(256, 2)
void maf_main(const float* __restrict__ U, const float* __restrict__ b3,
              const ushort* __restrict__ W2f2, const ushort* __restrict__ W2g2,
              const ushort* __restrict__ W1f, const ushort* __restrict__ W3f,
              const float* __restrict__ b1s2, const float* __restrict__ b1e,
              const float* __restrict__ b2s2, const float* __restrict__ b2e,
              float* __restrict__ out)
{
    __shared__ char smem[4*1024 + 4*1024 + 4*1024 + 4*2304 + 4*64];  // 21.8 KB/WG
    const int tid = threadIdx.x;
    const int w = tid >> 6, lane = tid & 63;
    const int r16 = lane & 15, q = lane >> 4;
    const int lane16 = lane << 4;
    char*   stgm = smem + w * 1024;                      // chunk-pair transpose staging
    char*   stge = smem + 4096 + w * 1024;               // extras staging (accumulating)
    char*   h2s  = smem + 8192 + w * 1024;               // h2 group staging
    ushort* xbs  = (ushort*)(smem + 12288 + w * 2304);   // [16][72] bf16 x mirror
    float*  lgd  = (float*)(smem + 21504 + w * 64);      // [16] logdet
    const int grow0 = blockIdx.x * 64 + w * 16;

    {
        u32x4 z = {0u, 0u, 0u, 0u};
        for (int i = lane; i < 64; i += 64) *(u32x4*)(stge + i * 16) = z;       // 1KB
        for (int i = lane; i < 64; i += 64) *(u32x4*)(h2s + i * 16) = z;        // 1KB
        for (int i = lane; i < 576; i += 64) ((uint32_t*)xbs)[i] = 0u;          // 2304B
        if (lane < 16) lgd[lane] = 0.f;
    }

    bf16x8 h1f[33];
    #pragma unroll
    for (int i = 0; i < 33; ++i) h1f[i] = (bf16x8){0,0,0,0,0,0,0,0};

    // output acc: am = mu cols (0..63), al = ls cols (64..127); tile n = cols n*16..
    f32x4 am0={0,0,0,0},am1={0,0,0,0},am2={0,0,0,0},am3={0,0,0,0};
    f32x4 al0={0,0,0,0},al1={0,0,0,0},al2={0,0,0,0},al3={0,0,0,0};

    for (int t = 0; t < 64; ++t) {
        const int tt = t >> 4, oc = t & 15;
        const float b3mu = b3[t], b3ls = b3[64 + t];
        float uu[4] = {0.f, 0.f, 0.f, 0.f};
        if (r16 == oc) {
            #pragma unroll
            for (int e = 0; e < 4; ++e)
                uu[e] = U[(size_t)(grow0 + q * 4 + e) * 64 + t];
        }

        if (t > 0) {
            const int d = t - 1;
            const int jc = d >> 1;

            // ---- phase a (MFMA): finalize h1 group d ----
            {
                const char* w1p = (const char*)W1f + (size_t)d * 4096 + lane16;
                bf16x8 wf00 = *(const bf16x8*)(w1p);
                bf16x8 wf10 = *(const bf16x8*)(w1p + 2048);
                bf16x8 xa0 = *(const bf16x8*)(xbs + r16 * 72 + q * 8);
                bf16x8 xa1 = *(const bf16x8*)(xbs + r16 * 72 + 32 + q * 8);
                f32x4 h = {0,0,0,0};
                h = MFMA(xa0, wf00, h, 0, 0, 0);
                h = MFMA(xa1, wf10, h, 0, 0, 0);
                float bb1 = b1s2[d * 16 + r16];
                #pragma unroll
                for (int e = 0; e < 4; ++e) {
                    int row = q * 4 + e;
                    ushort hv = f2bf(fmaxf(h[e] + bb1, 0.f));
                    *(ushort*)(stgm + ((row * 64 + ((d & 1) << 5) + r16 * 2) ^ ((row & 3) << 4))) = hv;
                    if (!(d & 1))
                        *(ushort*)(stgm + ((row * 64 + 32 + r16 * 2) ^ ((row & 3) << 4))) = 0;
                }
                if (d < 16) {                              // extra (17th) unit
                    bf16x8 wf01 = *(const bf16x8*)(w1p + 1024);
                    bf16x8 wf11 = *(const bf16x8*)(w1p + 3072);
                    f32x4 g = {0,0,0,0};
                    g = MFMA(xa0, wf01, g, 0, 0, 0);
                    g = MFMA(xa1, wf11, g, 0, 0, 0);
                    if (r16 == 0) {
                        float be = b1e[d];
                        #pragma unroll
                        for (int e = 0; e < 4; ++e) {
                            int row = q * 4 + e;
                            ushort hv = f2bf(fmaxf(g[e] + be, 0.f));
                            *(ushort*)(stge + ((row * 64 + d * 2) ^ ((row & 3) << 4))) = hv;
                        }
                    }
                }
            }
            // read back updated chunk frag(s) into registers
            {
                bf16x8 nf = *(const bf16x8*)(stgm + ((r16 * 64 + q * 16) ^ ((r16 & 3) << 4)));
                switch (jc) {
                    case 0:  h1f[0]=nf;  break; case 1:  h1f[1]=nf;  break;
                    case 2:  h1f[2]=nf;  break; case 3:  h1f[3]=nf;  break;
                    case 4:  h1f[4]=nf;  break; case 5:  h1f[5]=nf;  break;
                    case 6:  h1f[6]=nf;  break; case 7:  h1f[7]=nf;  break;
                    case 8:  h1f[8]=nf;  break; case 9:  h1f[9]=nf;  break;
                    case 10: h1f[10]=nf; break; case 11: h1f[11]=nf; break;
                    case 12: h1f[12]=nf; break; case 13: h1f[13]=nf; break;
                    case 14: h1f[14]=nf; break; case 15: h1f[15]=nf; break;
                    case 16: h1f[16]=nf; break; case 17: h1f[17]=nf; break;
                    case 18: h1f[18]=nf; break; case 19: h1f[19]=nf; break;
                    case 20: h1f[20]=nf; break; case 21: h1f[21]=nf; break;
                    case 22: h1f[22]=nf; break; case 23: h1f[23]=nf; break;
                    case 24: h1f[24]=nf; break; case 25: h1f[25]=nf; break;
                    case 26: h1f[26]=nf; break; case 27: h1f[27]=nf; break;
                    case 28: h1f[28]=nf; break; case 29: h1f[29]=nf; break;
                    case 30: h1f[30]=nf; break; default: h1f[31]=nf; break;
                }
                if (d < 16)
                    h1f[32] = *(const bf16x8*)(stge + ((r16 * 64 + q * 16) ^ ((r16 & 3) << 4)));
            }

            // ---- phase b (MFMA, register A-frags, streamed B-frags) ----
            f32x4 o1, o2 = {0,0,0,0};
            const char* w2p = (const char*)W2f2 + (size_t)d * 33 * 1024;
            const char* w2gp = (const char*)W2g2 + (size_t)d * 9 * 1024;
            if (t <= 16)      phase_b<8,  true >(w2p, w2gp, h1f, lane16, o1, o2);
            else if (t <= 28) phase_b<14, false>(w2p, w2gp, h1f, lane16, o1, o2);
            else if (t <= 40) phase_b<20, false>(w2p, w2gp, h1f, lane16, o1, o2);
            else if (t <= 52) phase_b<26, false>(w2p, w2gp, h1f, lane16, o1, o2);
            else              phase_b<32, false>(w2p, w2gp, h1f, lane16, o1, o2);

            // ---- phase c: W3 loads early, h2 transpose staging, 8 MFMAs ----
            {
                const char* w3p = (const char*)W3f + (size_t)d * 8192 + lane16;
                bf16x8 f0 = *(const bf16x8*)(w3p);
                bf16x8 f1 = *(const bf16x8*)(w3p + 1024);
                bf16x8 f2 = *(const bf16x8*)(w3p + 2048);
                bf16x8 f3 = *(const bf16x8*)(w3p + 3072);
                bf16x8 f4 = *(const bf16x8*)(w3p + 4096);
                bf16x8 f5 = *(const bf16x8*)(w3p + 5120);
                bf16x8 f6 = *(const bf16x8*)(w3p + 6144);
                bf16x8 f7 = *(const bf16x8*)(w3p + 7168);
                float bb2 = b2s2[d * 16 + r16];
                #pragma unroll
                for (int e = 0; e < 4; ++e) {
                    int row = q * 4 + e;
                    ushort hv = f2bf(fmaxf(o1[e] + bb2, 0.f));
                    *(ushort*)(h2s + ((row * 64 + r16 * 2) ^ ((row & 3) << 4))) = hv;
                }
                if (r16 == 0) {
                    float be2 = (d < 16) ? b2e[d] : 0.f;
                    #pragma unroll
                    for (int e = 0; e < 4; ++e) {
                        int row = q * 4 + e;
                        ushort hv = (d < 16) ? f2bf(fmaxf(o2[e] + be2, 0.f)) : (ushort)0;
                        *(ushort*)(h2s + ((row * 64 + 32) ^ ((row & 3) << 4))) = hv;
                    }
                }
                bf16x8 ha = *(const bf16x8*)(h2s + ((r16 * 64 + q * 16) ^ ((r16 & 3) << 4)));
                __builtin_amdgcn_s_setprio(1);
                am0 = MFMA(ha, f0, am0, 0, 0, 0);
                am1 = MFMA(ha, f1, am1, 0, 0, 0);
                am2 = MFMA(ha, f2, am2, 0, 0, 0);
                am3 = MFMA(ha, f3, am3, 0, 0, 0);
                al0 = MFMA(ha, f4, al0, 0, 0, 0);
                al1 = MFMA(ha, f5, al1, 0, 0, 0);
                al2 = MFMA(ha, f6, al2, 0, 0, 0);
                al3 = MFMA(ha, f7, al3, 0, 0, 0);
                __builtin_amdgcn_s_setprio(0);
            }
        }

        // ---- phase d: col t is final; owner lanes form x_t ----
        {
            f32x4 vm = (tt == 0) ? am0 : (tt == 1) ? am1 : (tt == 2) ? am2 : am3;
            f32x4 vl = (tt == 0) ? al0 : (tt == 1) ? al1 : (tt == 2) ? al2 : al3;
            if (r16 == oc) {
                #pragma unroll
                for (int e = 0; e < 4; ++e) {
                    int row = q * 4 + e;
                    float mu = vm[e] + b3mu;
                    float ls = vl[e] + b3ls;
                    float xv = uu[e] * expf(ls) + mu;
                    out[(size_t)(grow0 + row) * 64 + t] = xv;
                    xbs[row * 72 + t] = f2bf(xv);
                    lgd[row] += ls;
                }
            }
        }
    }

    if (lane < 16) out[(size_t)32768 * 64 + grow0 + lane] = lgd[lane];
}

extern "C" void kernel_launch(void* const* d_in, const int* in_sizes, int n_in,
                              void* d_out, int out_size, void* d_ws, size_t ws_size,
                              hipStream_t stream) {
    const float* U  = (const float*)d_in[0];
    const float* W1 = (const float*)d_in[1];
    const float* b1 = (const float*)d_in[2];
    const float* W2 = (const float*)d_in[3];
    const float* b2 = (const float*)d_in[4];
    const float* W3 = (const float*)d_in[5];
    const float* b3 = (const float*)d_in[6];
    float* out = (float*)d_out;

    char* ws = (char*)d_ws;
    ushort* W2f2 = (ushort*)ws;                      // 2,128,896 B
    ushort* W2g2 = (ushort*)(ws + 2128896);          //   147,456 B
    ushort* W1f  = (ushort*)(ws + 2276352);          //   258,048 B
    ushort* W3f  = (ushort*)(ws + 2534400);          //   516,096 B
    float*  b1s2 = (float*)(ws + 3050496);           //     4,096 B (1008 used)
    float*  b1e  = (float*)(ws + 3054592);           //       128 B
    float*  b2s2 = (float*)(ws + 3054720);           //     4,032 B
    float*  b2e  = (float*)(ws + 3058752);           //        64 B

    prep_all<<<4160, 256, 0, stream>>>(W1, W2, W3, b1, b2,
                                       W2f2, W2g2, W1f, W3f, b1s2, b1e, b2s2, b2e);
    maf_main<<<512, 256, 0, stream>>>(U, b3, W2f2, W2g2, W1f, W3f,
                                      b1s2, b1e, b2s2, b2e, out);
}